// Round 2
// baseline (148.344 us; speedup 1.0000x reference)
//
#include <hip/hip_runtime.h>

using bf16x8 = __attribute__((ext_vector_type(8))) short;
using f32x4  = __attribute__((ext_vector_type(4))) float;

#define NTREES   100
#define KDIM     128
#define TC       4
#define NCHUNKS  25
#define BM       64

// ws B layout: [chunk 25][half 2][sec 2 (hi,lo)][8192 shorts, swizzled]
//   element (c_l in 0..127, kk in 0..63): short idx = (c_l*64 + kk) ^ ((c_l&7)<<3)
//   -> linear global_load_lds + XOR-swizzled ds_read_b128 = conflict-free (G21/m201 pattern)
// LDS: [0, 32768)           B staging (hi sec 16384 | lo sec 16384); wave w owns
//                           bytes [w*4096,+4096) of each sec.  Re-used per wave as the
//                           h tile (XOR-swizzled) and finally as the reduction buffer.
//      [32768, 32768+17408) x_hi tile [64 rows][136 shorts] (read-only after prologue)
#define XH_OFF 32768
#define XSTR   136
#define LDS_BYTES (XH_OFF + 64 * XSTR * 2)   // 50176 -> 3 blocks/CU

__device__ __forceinline__ void split_bf16(float v, unsigned short& h, unsigned short& l) {
  unsigned u = __float_as_uint(v);
  unsigned r = u + 0x7FFFu + ((u >> 16) & 1u);          // RNE to bf16
  unsigned short hu = (unsigned short)(r >> 16);
  float hf = __uint_as_float((unsigned)hu << 16);
  float res = v - hf;
  unsigned u2 = __float_as_uint(res);
  unsigned r2 = u2 + 0x7FFFu + ((u2 >> 16) & 1u);
  h = hu;
  l = (unsigned short)(r2 >> 16);
}

__device__ __forceinline__ void gload_lds16(const void* g, void* l) {
  __builtin_amdgcn_global_load_lds((const __attribute__((address_space(1))) void*)g,
                                   (__attribute__((address_space(3))) void*)l, 16, 0, 0);
}

// kernel[T][F][31] f32 -> swizzled bf16 hi/lo split, scaled by 100 (1/tau)
__global__ void prep_b(const float* __restrict__ kern, unsigned short* __restrict__ bws) {
  const int t = blockIdx.x;            // tree
  const int f = threadIdx.x;           // k index 0..127
  const int H = f >> 6, kk = f & 63;
  const float* src = kern + (size_t)t * (KDIM * 31) + (size_t)f * 31;
  unsigned short* hi = bws + (size_t)(t >> 2) * 32768 + (size_t)H * 16384;
  unsigned short* lo = hi + 8192;
  #pragma unroll
  for (int n = 0; n < 32; ++n) {
    float v = (n < 31) ? src[n] * 100.0f : 0.0f;
    unsigned short hh, ll;
    split_bf16(v, hh, ll);
    const int c_l = ((t & 3) << 5) + n;
    const int idx = ((c_l << 6) + kk) ^ ((c_l & 7) << 3);
    hi[idx] = hh;
    lo[idx] = ll;
  }
}

__global__ __launch_bounds__(256, 3) void gbm_main(
    const float* __restrict__ x,
    const unsigned short* __restrict__ bws,
    const float* __restrict__ bias,
    const float* __restrict__ leaf,
    float* __restrict__ out)
{
  __shared__ __align__(16) unsigned char lds[LDS_BYTES];
  float* red = (float*)lds;

  const int tid  = threadIdx.x;
  const int lane = tid & 63;
  const int w    = tid >> 6;                 // wave id = tree slot in chunk
  const int rowbase = blockIdx.x * BM;

  // ---- prologue: load x rows, split; a_lo -> regs, x_hi -> LDS (wave 0 writes) ----
  bf16x8 a_lo[4][4];
  {
    const int r0 = lane & 15;
    const int kb = (lane >> 4) * 8;
    #pragma unroll
    for (int rt = 0; rt < 4; ++rt) {
      const float* px = x + (size_t)(rowbase + r0 + rt * 16) * KDIM + kb;
      #pragma unroll
      for (int ks = 0; ks < 4; ++ks) {
        float4 v0 = *(const float4*)(px + ks * 32);
        float4 v1 = *(const float4*)(px + ks * 32 + 4);
        float vals[8] = {v0.x, v0.y, v0.z, v0.w, v1.x, v1.y, v1.z, v1.w};
        bf16x8 h8, l8;
        #pragma unroll
        for (int j = 0; j < 8; ++j) {
          unsigned short hu, lu;
          split_bf16(vals[j], hu, lu);
          h8[j] = (short)hu;
          l8[j] = (short)lu;
        }
        a_lo[rt][ks] = l8;
        if (w == 0)
          *(bf16x8*)(lds + XH_OFF + (size_t)(r0 + rt * 16) * (XSTR * 2) + (ks * 32 + kb) * 2) = h8;
      }
    }
  }
  __syncthreads();   // x_hi visible to all waves; ONLY barrier until the final reduce

  float outAcc = 0.0f;

  for (int c = 0; c < NCHUNKS; ++c) {
    f32x4 acc[4][2] = {};

    #pragma unroll
    for (int H = 0; H < 2; ++H) {
      // prior ds_reads of this wave's slice must retire before DMA overwrites it
      asm volatile("s_waitcnt lgkmcnt(0)" ::: "memory");
      __builtin_amdgcn_sched_barrier(0);
      const unsigned char* gsb = (const unsigned char*)bws + (size_t)c * 65536 + (size_t)H * 32768;
      #pragma unroll
      for (int s2 = 0; s2 < 2; ++s2)
        #pragma unroll
        for (int j = 0; j < 4; ++j)
          gload_lds16(gsb + s2 * 16384 + w * 4096 + j * 1024 + lane * 16,
                      lds + s2 * 16384 + w * 4096 + j * 1024);
      asm volatile("s_waitcnt vmcnt(0)" ::: "memory");
      __builtin_amdgcn_sched_barrier(0);

      #pragma unroll
      for (int ksl = 0; ksl < 2; ++ksl) {
        const int ks  = H * 2 + ksl;
        const int kk  = ksl * 32 + ((lane >> 4) << 3);
        const int c0  = (w << 5) + (lane & 15);
        const int i0  = (((c0 << 6) + kk) ^ ((c0 & 7) << 3)) * 2;   // byte offset in hi sec
        bf16x8 bh0 = *(const bf16x8*)(lds + i0);
        bf16x8 bh1 = *(const bf16x8*)(lds + i0 + 2048);             // c0+16: +1024 shorts
        bf16x8 bl0 = *(const bf16x8*)(lds + 16384 + i0);
        bf16x8 bl1 = *(const bf16x8*)(lds + 16384 + i0 + 2048);
        const int xko = (ks * 32 + ((lane >> 4) << 3)) * 2;
        #pragma unroll
        for (int rt = 0; rt < 4; ++rt) {
          bf16x8 ah = *(const bf16x8*)(lds + XH_OFF + (size_t)((lane & 15) + rt * 16) * (XSTR * 2) + xko);
          acc[rt][0] = __builtin_amdgcn_mfma_f32_16x16x32_bf16(ah,            bh0, acc[rt][0], 0, 0, 0);
          acc[rt][0] = __builtin_amdgcn_mfma_f32_16x16x32_bf16(a_lo[rt][ks],  bh0, acc[rt][0], 0, 0, 0);
          acc[rt][0] = __builtin_amdgcn_mfma_f32_16x16x32_bf16(ah,            bl0, acc[rt][0], 0, 0, 0);
          acc[rt][1] = __builtin_amdgcn_mfma_f32_16x16x32_bf16(ah,            bh1, acc[rt][1], 0, 0, 0);
          acc[rt][1] = __builtin_amdgcn_mfma_f32_16x16x32_bf16(a_lo[rt][ks],  bh1, acc[rt][1], 0, 0, 0);
          acc[rt][1] = __builtin_amdgcn_mfma_f32_16x16x32_bf16(ah,            bl1, acc[rt][1], 0, 0, 0);
        }
      }
    }

    // ---- scatter h into THIS WAVE'S B slice (XOR-swizzled, wave-private) ----
    // byte = w*4096 + (row>=32)*16384 + (((row&31)*128 + col*4) ^ ((row&7)<<4))
    {
      const int hr = (lane >> 4) << 2;
      const int hc = lane & 15;
      #pragma unroll
      for (int rt = 0; rt < 4; ++rt) {
        const int sb = (w << 12) + ((rt >> 1) << 14);
        #pragma unroll
        for (int ct = 0; ct < 2; ++ct)
          #pragma unroll
          for (int r = 0; r < 4; ++r) {
            const int row = rt * 16 + hr + r;
            const int inner = (((row & 31) << 7) + ((ct * 16 + hc) << 2)) ^ ((row & 7) << 4);
            *(float*)(lds + sb + inner) = acc[rt][ct][r];
          }
      }
    }

    // ---- read back own row (lane = row), wave-local dependency only ----
    f32x4 hv[8];
    {
      const int sb = (w << 12) + ((lane >> 5) << 14);
      #pragma unroll
      for (int g = 0; g < 8; ++g) {
        const int inner = (((lane & 31) << 7) + (g << 4)) ^ ((lane & 7) << 4);
        hv[g] = *(const f32x4*)(lds + sb + inner);
      }
    }

    // ---- tree eval ----
    {
      const int tree = c * TC + w;
      const float* bp = bias + (size_t)tree * 31;
      const float* lp = leaf + (size_t)tree * 32;
      float cum[32];
      cum[0] = 1.0f;
      #pragma unroll
      for (int d = 0; d < 5; ++d) {
        #pragma unroll
        for (int i = (1 << d) - 1; i >= 0; --i) {
          const int node = (1 << d) - 1 + i;
          float z = fmaf(bp[node], 100.0f, hv[node >> 2][node & 3]);
          z = fmaxf(z, -20.0f);                         // sub-eps floor; avoids exp overflow
          float e  = __expf(-z);
          float sl = __builtin_amdgcn_rcpf(1.0f + e);   // sigma(z)  -> left
          float sr = e * sl;                            // sigma(-z) -> right
          float cl = cum[i];
          cum[2 * i]     = cl * sl;
          cum[2 * i + 1] = cl * sr;
        }
      }
      float s = 0.0f;
      #pragma unroll
      for (int l = 0; l < 32; ++l)
        s = fmaf(cum[l], lp[l], s);
      outAcc += s;
    }
  }

  // ---- reduce the 4 tree-slot partials per row, write out ----
  __syncthreads();
  red[tid] = outAcc;
  __syncthreads();
  if (tid < 64)
    out[rowbase + tid] = red[tid] + red[tid + 64] + red[tid + 128] + red[tid + 192];
}

extern "C" void kernel_launch(void* const* d_in, const int* in_sizes, int n_in,
                              void* d_out, int out_size, void* d_ws, size_t ws_size,
                              hipStream_t stream) {
  const float* x    = (const float*)d_in[0];
  const float* kern = (const float*)d_in[1];
  const float* bias = (const float*)d_in[2];
  const float* leaf = (const float*)d_in[3];
  // d_in[4] = route: topology hard-coded (perfect depth-5 tree, bit0=left)

  unsigned short* bws = (unsigned short*)d_ws;   // 25*65536 B = 1.64 MB

  prep_b<<<NTREES, 128, 0, stream>>>(kern, bws);
  gbm_main<<<32768 / BM, 256, 0, stream>>>(x, bws, bias, leaf, (float*)d_out);
}

// Round 3
// 98.672 us; speedup vs baseline: 1.5034x; 1.5034x over previous
//
#include <hip/hip_runtime.h>

using bf16x8 = __attribute__((ext_vector_type(8))) short;
using f32x4  = __attribute__((ext_vector_type(4))) float;

#define NTREES   100
#define KDIM     128
#define TC       4
#define NCHUNKS  25
#define BM       64

// ws B layout: per tree t (8192 shorts at bws + t*8192):
//   idx = ks*2048 + frag*512 + lane*8 + j      (ks 0..3, frag 0..3, lane 0..63, j 0..7)
//   frag 0/1 = hi-split cols (lane&15) / 16+(lane&15); frag 2/3 = lo-split same cols
//   k = ks*32 + (lane>>4)*8 + j; value = kernel[t][k][col]*100, col 31 -> 0 pad
// -> wave w loads its tree's B fragments as 16 coalesced global_load_dwordx4, no LDS.

__device__ __forceinline__ void split_bf16(float v, unsigned short& h, unsigned short& l) {
  unsigned u = __float_as_uint(v);
  unsigned r = u + 0x7FFFu + ((u >> 16) & 1u);          // RNE to bf16
  unsigned short hu = (unsigned short)(r >> 16);
  float hf = __uint_as_float((unsigned)hu << 16);
  float res = v - hf;
  unsigned u2 = __float_as_uint(res);
  unsigned r2 = u2 + 0x7FFFu + ((u2 >> 16) & 1u);
  h = hu;
  l = (unsigned short)(r2 >> 16);
}

__global__ void prep_b(const float* __restrict__ kern, unsigned short* __restrict__ bws) {
  __shared__ float kt[KDIM][33];
  const int t = blockIdx.x, tid = threadIdx.x;
  const float* src = kern + (size_t)t * (KDIM * 31);
  for (int i = tid; i < KDIM * 31; i += 256) {
    int f = i / 31, n = i - f * 31;
    kt[f][n] = src[i] * 100.0f;
  }
  for (int f = tid; f < KDIM; f += 256) kt[f][31] = 0.0f;   // pad col
  __syncthreads();
  unsigned short* dst = bws + (size_t)t * 8192;
  for (int s = tid; s < 1024; s += 256) {
    const int ks = s >> 8, frag = (s >> 6) & 3, lane = s & 63;
    const int n  = ((frag & 1) << 4) + (lane & 15);
    const int k0 = ks * 32 + ((lane >> 4) << 3);
    bf16x8 o;
    #pragma unroll
    for (int j = 0; j < 8; ++j) {
      unsigned short hh, ll;
      split_bf16(kt[k0 + j][n], hh, ll);
      o[j] = (short)((frag >= 2) ? ll : hh);
    }
    *(bf16x8*)(dst + s * 8) = o;
  }
}

__device__ __forceinline__ void sig2(float z, float& sl, float& sr) {
  z = fmaxf(z, -20.0f);                     // guard exp overflow; sub-eps regime anyway
  float e = __expf(-z);
  sl = __builtin_amdgcn_rcpf(1.0f + e);     // sigma(z)  -> left
  sr = e * sl;                              // sigma(-z) -> right
}

__global__ __launch_bounds__(256, 2) void gbm_main(
    const float* __restrict__ x,
    const unsigned short* __restrict__ bws,
    const float* __restrict__ bias,
    const float* __restrict__ leaf,
    float* __restrict__ out)
{
  // LDS: wave-private h transpose tiles only. 4 waves x 8192 B.
  // h byte (within wave slice) = (row*128 + col*4) ^ ((row&7)<<4)
  //   writes: 2 lanes/bank (free); b128 reads: 1 KB/instr floor.
  __shared__ __align__(16) unsigned char lds[4 * 8192];
  float* red = (float*)lds;

  const int tid  = threadIdx.x;
  const int lane = tid & 63;
  const int w    = tid >> 6;                 // wave id = tree slot in chunk
  const int rowbase = blockIdx.x * BM;
  unsigned char* hslice = lds + (w << 13);

  // ---- prologue: load x rows, split to persistent A fragments (regs only) ----
  bf16x8 a_hi[4][4], a_lo[4][4];
  {
    const int r0 = lane & 15;
    const int kb = (lane >> 4) * 8;
    #pragma unroll
    for (int rt = 0; rt < 4; ++rt) {
      const float* px = x + (size_t)(rowbase + r0 + rt * 16) * KDIM + kb;
      #pragma unroll
      for (int ks = 0; ks < 4; ++ks) {
        float4 v0 = *(const float4*)(px + ks * 32);
        float4 v1 = *(const float4*)(px + ks * 32 + 4);
        float vals[8] = {v0.x, v0.y, v0.z, v0.w, v1.x, v1.y, v1.z, v1.w};
        bf16x8 h8, l8;
        #pragma unroll
        for (int j = 0; j < 8; ++j) {
          unsigned short hu, lu;
          split_bf16(vals[j], hu, lu);
          h8[j] = (short)hu;
          l8[j] = (short)lu;
        }
        a_hi[rt][ks] = h8;
        a_lo[rt][ks] = l8;
      }
    }
  }

  const unsigned short* bbase = bws + (size_t)w * 8192;

  // ---- preload chunk 0 B fragments into registers ----
  bf16x8 breg[16];
  #pragma unroll
  for (int i = 0; i < 16; ++i)
    breg[i] = *(const bf16x8*)(bbase + (size_t)i * 512 + lane * 8);

  float outAcc = 0.0f;

  for (int c = 0; c < NCHUNKS; ++c) {
    // ---- MFMA: 3-pass bf16 split GEMM for this wave's tree ----
    f32x4 acc[4][2] = {};
    #pragma unroll
    for (int ks = 0; ks < 4; ++ks) {
      bf16x8 bh0 = breg[ks * 4 + 0], bh1 = breg[ks * 4 + 1];
      bf16x8 bl0 = breg[ks * 4 + 2], bl1 = breg[ks * 4 + 3];
      #pragma unroll
      for (int rt = 0; rt < 4; ++rt) {
        acc[rt][0] = __builtin_amdgcn_mfma_f32_16x16x32_bf16(a_hi[rt][ks], bh0, acc[rt][0], 0, 0, 0);
        acc[rt][0] = __builtin_amdgcn_mfma_f32_16x16x32_bf16(a_lo[rt][ks], bh0, acc[rt][0], 0, 0, 0);
        acc[rt][0] = __builtin_amdgcn_mfma_f32_16x16x32_bf16(a_hi[rt][ks], bl0, acc[rt][0], 0, 0, 0);
        acc[rt][1] = __builtin_amdgcn_mfma_f32_16x16x32_bf16(a_hi[rt][ks], bh1, acc[rt][1], 0, 0, 0);
        acc[rt][1] = __builtin_amdgcn_mfma_f32_16x16x32_bf16(a_lo[rt][ks], bh1, acc[rt][1], 0, 0, 0);
        acc[rt][1] = __builtin_amdgcn_mfma_f32_16x16x32_bf16(a_hi[rt][ks], bl1, acc[rt][1], 0, 0, 0);
      }
    }

    // ---- scatter h to wave-private swizzled LDS (D: col=lane&15, row=(lane>>4)*4+r) ----
    {
      const int hr = (lane >> 4) << 2;
      const int hc = lane & 15;
      #pragma unroll
      for (int rt = 0; rt < 4; ++rt)
        #pragma unroll
        for (int ct = 0; ct < 2; ++ct)
          #pragma unroll
          for (int r = 0; r < 4; ++r) {
            const int row = rt * 16 + hr + r;
            const int col = ct * 16 + hc;
            *(float*)(hslice + ((row * 128 + col * 4) ^ ((row & 7) << 4))) = acc[rt][ct][r];
          }
    }

    // ---- issue next chunk's B loads (WAR on breg orders them after the MFMAs;
    //      tree-eval below covers the L2 latency; no vmcnt(0) stall) ----
    if (c + 1 < NCHUNKS) {
      const unsigned short* nb = bbase + (size_t)(c + 1) * 32768;
      #pragma unroll
      for (int i = 0; i < 16; ++i)
        breg[i] = *(const bf16x8*)(nb + (size_t)i * 512 + lane * 8);
    }

    // ---- read back own row (lane = row) ----
    f32x4 hv[8];
    #pragma unroll
    for (int g = 0; g < 8; ++g)
      hv[g] = *(const f32x4*)(hslice + ((lane * 128 + g * 16) ^ ((lane & 7) << 4)));

    // ---- tree eval: cum to depth 3, leaf dot fused into depth 4 ----
    {
      const int tree = __builtin_amdgcn_readfirstlane(c * TC + w);
      const float* bp = bias + (size_t)tree * 31;
      const float* lp = leaf + (size_t)tree * 32;
      float cum[16];
      cum[0] = 1.0f;
      #pragma unroll
      for (int d = 0; d < 4; ++d) {
        #pragma unroll
        for (int i = (1 << d) - 1; i >= 0; --i) {
          const int node = (1 << d) - 1 + i;
          float sl, sr;
          sig2(fmaf(bp[node], 100.0f, hv[node >> 2][node & 3]), sl, sr);
          float cl = cum[i];
          cum[2 * i]     = cl * sl;
          cum[2 * i + 1] = cl * sr;
        }
      }
      float s = 0.0f;
      #pragma unroll
      for (int i = 0; i < 16; ++i) {
        const int node = 15 + i;
        float sl, sr;
        sig2(fmaf(bp[node], 100.0f, hv[node >> 2][node & 3]), sl, sr);
        s = fmaf(cum[i], fmaf(sl, lp[2 * i], sr * lp[2 * i + 1]), s);
      }
      outAcc += s;
    }
  }

  // ---- reduce the 4 tree-slot partials per row, write out ----
  __syncthreads();
  red[tid] = outAcc;
  __syncthreads();
  if (tid < 64)
    out[rowbase + tid] = red[tid] + red[tid + 64] + red[tid + 128] + red[tid + 192];
}

extern "C" void kernel_launch(void* const* d_in, const int* in_sizes, int n_in,
                              void* d_out, int out_size, void* d_ws, size_t ws_size,
                              hipStream_t stream) {
  const float* x    = (const float*)d_in[0];
  const float* kern = (const float*)d_in[1];
  const float* bias = (const float*)d_in[2];
  const float* leaf = (const float*)d_in[3];
  // d_in[4] = route: topology hard-coded (perfect depth-5 tree, bit0=left)

  unsigned short* bws = (unsigned short*)d_ws;   // 100*8192 shorts = 1.64 MB

  prep_b<<<NTREES, 256, 0, stream>>>(kern, bws);
  gbm_main<<<32768 / BM, 256, 0, stream>>>(x, bws, bias, leaf, (float*)d_out);
}

// Round 4
// 68.883 us; speedup vs baseline: 2.1536x; 1.4325x over previous
//
#include <hip/hip_runtime.h>

typedef _Float16 f16x8 __attribute__((ext_vector_type(8)));
typedef float    f32x4 __attribute__((ext_vector_type(4)));

#define NTREES  100
#define TC      4
#define NCHUNKS 25
#define BM      64
#define SCALE   144.269504088896f      // 100 * log2(e): z2 = z/tau * log2(e)

// LDS map (67584 B -> 2 blocks/CU):
//  [0,        17408)  A_hi [64 rows][136 shorts] (f16, first 128 cols used)
//  [17408,    34816)  A_lo  same layout
//  [34816,    67584)  h slices: wave w owns 8192 B at 34816 + w*8192
//  272-B row stride => 4-bank rotation/row => b128 reads/writes at 1KB/instr floor
#define XSTR   136
#define AL_OFF (64 * XSTR * 2)
#define H_OFF  (2 * 64 * XSTR * 2)
#define LDS_BYTES (H_OFF + 4 * 8192)

__device__ __forceinline__ float exp2_fast(float v) {
#if __has_builtin(__builtin_amdgcn_exp2f)
  return __builtin_amdgcn_exp2f(v);
#else
  return exp2f(v);
#endif
}

// sigma pair in base-2 domain: sl = 1/(1+2^-z), sr = 1 - sl
__device__ __forceinline__ void sig2(float z, float& sl, float& sr) {
  z = fmaxf(z, -24.0f);                     // guard inf/NaN; ref eps-clip regime anyway
  float e = exp2_fast(-z);
  sl = __builtin_amdgcn_rcpf(1.0f + e);
  sr = e * sl;
}

// kernel[T][128][31] f32 -> per-lane f16 fragment order, scaled by 100*log2e:
//   per tree t: 4096 shorts; idx = ks*1024 + frag*512 + lane*8 + j
//   frag 0/1 = cols (lane&15) / 16+(lane&15); k = ks*32 + (lane>>4)*8 + j; col 31 -> 0
__global__ void prep_b(const float* __restrict__ kern, unsigned short* __restrict__ bws) {
  __shared__ float kt[128][33];
  const int t = blockIdx.x, tid = threadIdx.x;
  const float* src = kern + (size_t)t * (128 * 31);
  for (int i = tid; i < 128 * 31; i += 256) {
    int f = i / 31, n = i - f * 31;
    kt[f][n] = src[i] * SCALE;
  }
  for (int f = tid; f < 128; f += 256) kt[f][31] = 0.0f;
  __syncthreads();
  unsigned short* dst = bws + (size_t)t * 4096;
  for (int s = tid; s < 512; s += 256) {
    const int ks = s >> 7, frag = (s >> 6) & 1, lane = s & 63;
    const int n  = (frag << 4) + (lane & 15);
    const int k0 = ks * 32 + ((lane >> 4) << 3);
    f16x8 o;
    #pragma unroll
    for (int j = 0; j < 8; ++j) o[j] = (_Float16)kt[k0 + j][n];
    *(f16x8*)(dst + s * 8) = o;
  }
}

__global__ __launch_bounds__(256, 2) void gbm_main(
    const float* __restrict__ x,
    const unsigned short* __restrict__ bws,
    const float* __restrict__ bias,
    const float* __restrict__ leaf,
    float* __restrict__ out)
{
  __shared__ __align__(16) unsigned char lds[LDS_BYTES];
  float* red = (float*)lds;

  const int tid  = threadIdx.x;
  const int lane = tid & 63;
  const int w    = tid >> 6;                 // wave id = tree slot in chunk
  const int rowbase = blockIdx.x * BM;
  unsigned char* hsl = lds + H_OFF + (w << 13);

  // ---- prologue: wave w stages A rows w*16..+15 as f16 hi/lo into LDS ----
  {
    const int row = (w << 4) + (lane & 15);
    const int kb  = (lane >> 4) << 3;
    const float* px = x + (size_t)(rowbase + row) * 128 + kb;
    #pragma unroll
    for (int ks = 0; ks < 4; ++ks) {
      float4 v0 = *(const float4*)(px + ks * 32);
      float4 v1 = *(const float4*)(px + ks * 32 + 4);
      float vals[8] = {v0.x, v0.y, v0.z, v0.w, v1.x, v1.y, v1.z, v1.w};
      f16x8 h8, l8;
      #pragma unroll
      for (int j = 0; j < 8; ++j) {
        _Float16 hh = (_Float16)vals[j];
        h8[j] = hh;
        l8[j] = (_Float16)(vals[j] - (float)hh);
      }
      const int off = (row * XSTR + ks * 32 + kb) * 2;
      *(f16x8*)(lds + off) = h8;
      *(f16x8*)(lds + AL_OFF + off) = l8;
    }
  }

  // ---- preload chunk 0 B fragments (8 x b128, L2-resident) ----
  const unsigned short* bbase = bws + (size_t)w * 4096;
  f16x8 breg[8];
  #pragma unroll
  for (int i = 0; i < 8; ++i)
    breg[i] = *(const f16x8*)(bbase + (size_t)i * 512 + lane * 8);

  __syncthreads();   // A tile visible; only barrier until the final reduce

  float outAcc = 0.0f;

  for (int c = 0; c < NCHUNKS; ++c) {
    // ---- 2-pass f16 split GEMM for this wave's tree ----
    f32x4 acc[4][2] = {};
    {
      const int ko = (lane >> 4) << 3;
      #pragma unroll
      for (int ks = 0; ks < 4; ++ks) {
        f16x8 b0 = breg[ks * 2], b1 = breg[ks * 2 + 1];
        const int kb = (ks * 32 + ko) * 2;
        #pragma unroll
        for (int rt = 0; rt < 4; ++rt) {
          const int ro = ((lane & 15) + (rt << 4)) * (XSTR * 2) + kb;
          f16x8 ah = *(const f16x8*)(lds + ro);
          f16x8 al = *(const f16x8*)(lds + AL_OFF + ro);
          acc[rt][0] = __builtin_amdgcn_mfma_f32_16x16x32_f16(ah, b0, acc[rt][0], 0, 0, 0);
          acc[rt][0] = __builtin_amdgcn_mfma_f32_16x16x32_f16(al, b0, acc[rt][0], 0, 0, 0);
          acc[rt][1] = __builtin_amdgcn_mfma_f32_16x16x32_f16(ah, b1, acc[rt][1], 0, 0, 0);
          acc[rt][1] = __builtin_amdgcn_mfma_f32_16x16x32_f16(al, b1, acc[rt][1], 0, 0, 0);
        }
      }
    }

    // ---- issue next chunk's B loads (WAR on breg orders after MFMAs;
    //      scatter+eval below covers the L2 latency) ----
    if (c + 1 < NCHUNKS) {
      const unsigned short* nb = bbase + (size_t)(c + 1) * 16384;
      #pragma unroll
      for (int i = 0; i < 8; ++i)
        breg[i] = *(const f16x8*)(nb + (size_t)i * 512 + lane * 8);
    }

    // ---- scatter h to wave-private swizzled slice (D: col=lane&15, row=(lane>>4)*4+r) ----
    {
      const int hr = (lane >> 4) << 2;
      const int hc = lane & 15;
      #pragma unroll
      for (int rt = 0; rt < 4; ++rt)
        #pragma unroll
        for (int ct = 0; ct < 2; ++ct)
          #pragma unroll
          for (int r = 0; r < 4; ++r) {
            const int row = rt * 16 + hr + r;
            const int col = ct * 16 + hc;
            *(float*)(hsl + ((row * 128 + col * 4) ^ ((row & 7) << 4))) = acc[rt][ct][r];
          }
    }

    // ---- read back own row (lane = row) ----
    f32x4 hv[8];
    #pragma unroll
    for (int g = 0; g < 8; ++g)
      hv[g] = *(const f32x4*)(hsl + ((lane * 128 + g * 16) ^ ((lane & 7) << 4)));

    // ---- tree eval: cum to depth 3, leaf dot fused into depth 4 ----
    {
      const int tree = __builtin_amdgcn_readfirstlane(c * TC + w);
      const float* bp = bias + (size_t)tree * 31;
      const float* lp = leaf + (size_t)tree * 32;
      float cum[16];
      cum[0] = 1.0f;
      #pragma unroll
      for (int d = 0; d < 4; ++d) {
        #pragma unroll
        for (int i = (1 << d) - 1; i >= 0; --i) {
          const int node = (1 << d) - 1 + i;
          float sl, sr;
          sig2(fmaf(bp[node], SCALE, hv[node >> 2][node & 3]), sl, sr);
          float cl = cum[i];
          cum[2 * i]     = cl * sl;
          cum[2 * i + 1] = cl * sr;
        }
      }
      float s = 0.0f;
      #pragma unroll
      for (int i = 0; i < 16; ++i) {
        const int node = 15 + i;
        float sl, sr;
        sig2(fmaf(bp[node], SCALE, hv[node >> 2][node & 3]), sl, sr);
        s = fmaf(cum[i], fmaf(sl, lp[2 * i], sr * lp[2 * i + 1]), s);
      }
      outAcc += s;
    }
  }

  // ---- reduce the 4 tree-slot partials per row, write out ----
  __syncthreads();
  red[tid] = outAcc;
  __syncthreads();
  if (tid < 64)
    out[rowbase + tid] = red[tid] + red[tid + 64] + red[tid + 128] + red[tid + 192];
}

extern "C" void kernel_launch(void* const* d_in, const int* in_sizes, int n_in,
                              void* d_out, int out_size, void* d_ws, size_t ws_size,
                              hipStream_t stream) {
  const float* x    = (const float*)d_in[0];
  const float* kern = (const float*)d_in[1];
  const float* bias = (const float*)d_in[2];
  const float* leaf = (const float*)d_in[3];
  // d_in[4] = route: topology hard-coded (perfect depth-5 tree, bit0=left)

  unsigned short* bws = (unsigned short*)d_ws;   // 100*4096 shorts = 819 KB

  prep_b<<<NTREES, 256, 0, stream>>>(kern, bws);
  gbm_main<<<32768 / BM, 256, 0, stream>>>(x, bws, bias, leaf, (float*)d_out);
}